// Round 3
// baseline (346.026 us; speedup 1.0000x reference)
//
#include <hip/hip_runtime.h>
#include <math.h>

typedef __attribute__((ext_vector_type(8))) short bf16x8;
typedef __attribute__((ext_vector_type(4))) float f32x4;

#define NB   8
#define CI   128
#define CO   128
#define KTOT 1152        // CI*9

#define NA_W  (32 * KTOT)        // wsA elems (w_off padded to 32 rows)
#define NB_W  (CO * KTOT)        // wsB elems
#define N_OFFM (NB * 27 * 4096)  // offm elems
#define N_OUT  (NB * CO * 4096)  // out elems

__device__ __forceinline__ unsigned short f2bf(float f) {
  union { float f; unsigned u; } v; v.f = f;
  unsigned r = v.u + 0x7FFF + ((v.u >> 16) & 1);   // RNE
  return (unsigned short)(r >> 16);
}

// ---------------- prep: bf16 weights + zero offm + bias-init out ----------------
__global__ void prep_kernel(const float* __restrict__ w_off,
                            const float* __restrict__ w_def,
                            const float* __restrict__ b_def,
                            unsigned short* __restrict__ wsA,
                            unsigned short* __restrict__ wsB,
                            float* __restrict__ offm,
                            float* __restrict__ out) {
  int i = blockIdx.x * 256 + threadIdx.x;
  if (i < NA_W) {
    int row = i / KTOT;
    wsA[i] = (row < 27) ? f2bf(w_off[i]) : (unsigned short)0;
  } else if (i < NA_W + NB_W) {
    wsB[i - NA_W] = f2bf(w_def[i - NA_W]);
  } else if (i < NA_W + NB_W + N_OFFM) {
    offm[i - NA_W - NB_W] = 0.0f;
  } else {
    int j = i - NA_W - NB_W - N_OFFM;
    out[j] = b_def[(j >> 12) & 127];
  }
}

// ---------------- finalize offm: +bias, sigmoid on mask channels ----------------
__global__ void finalize_offm(float* __restrict__ offm,
                              const float* __restrict__ b_off) {
  int i = blockIdx.x * 256 + threadIdx.x;   // N_OFFM threads
  int c = (i >> 12) % 27;
  float v = offm[i] + b_off[c];
  if (c >= 18) v = 1.0f / (1.0f + __expf(-v));
  offm[i] = v;
}

// ---------------- offset conv via MFMA, K-split 4, atomic accumulate ----------------
// grid 2048: block = (split, b, ho). M=32(pad27), N=64, K=288 per block.
#define KCO 96
#define LWO 104   // s_s row stride (shorts); 208 B = 16B-aligned

__global__ __launch_bounds__(256, 8)
void offset_conv_kernel(const float* __restrict__ x,
                        const unsigned short* __restrict__ wA,
                        float* __restrict__ offm) {
  __shared__ __align__(16) unsigned short s_s[64 * LWO];  // 13312 B
  const int t = threadIdx.x;
  const int bi = blockIdx.x & 511, split = blockIdx.x >> 9;
  const int b = bi >> 6, ho = bi & 63;
  const int lane = t & 63, wid = t >> 6;
  const int q = lane >> 4, li = lane & 15;
  const float* __restrict__ xb = x + (size_t)b * CI * 4096;
  const int kb = split * 288;
  const int mt = wid >> 1, nt0 = (wid & 1) * 2;

  f32x4 acc0 = {0.f, 0.f, 0.f, 0.f};
  f32x4 acc1 = {0.f, 0.f, 0.f, 0.f};

  for (int ch = 0; ch < 3; ++ch) {
    const int k0 = kb + ch * KCO;
    // prefetch A-fragments for this chunk (hidden under sampling)
    bf16x8 afr[3];
    #pragma unroll
    for (int ks = 0; ks < 3; ++ks)
      afr[ks] = *(const bf16x8*)&wA[(mt * 16 + li) * KTOT + k0 + ks * 32 + q * 8];
    __syncthreads();  // previous chunk's MFMA reads of s_s done
    // sampling: 12 k-groups x 64 px = 768 groups, 3 per thread, b128 stores
    #pragma unroll
    for (int g = 0; g < 3; ++g) {
      int f = t + g * 256;
      int px = f & 63, kg = f >> 6;     // kg 0..11
      int ki0 = kg * 8;
      bf16x8 vv;
      #pragma unroll
      for (int j = 0; j < 8; ++j) {
        int kk = k0 + ki0 + j;
        int cc = (int)((unsigned)kk / 9u);
        int k  = kk - cc * 9;
        int ky = k / 3, kx = k - ky * 3;
        int y  = ho + ky - 1, xx = px + kx - 1;
        float v = 0.f;
        if ((unsigned)y < 64u && (unsigned)xx < 64u) v = xb[cc * 4096 + y * 64 + xx];
        vv[j] = (short)f2bf(v);
      }
      *(bf16x8*)&s_s[px * LWO + ki0] = vv;
    }
    __syncthreads();
    #pragma unroll
    for (int ks = 0; ks < 3; ++ks) {
      const int kc = ks * 32 + q * 8;
      bf16x8 b0 = *(const bf16x8*)&s_s[((nt0    ) * 16 + li) * LWO + kc];
      bf16x8 b1 = *(const bf16x8*)&s_s[((nt0 + 1) * 16 + li) * LWO + kc];
      acc0 = __builtin_amdgcn_mfma_f32_16x16x32_bf16(afr[ks], b0, acc0, 0, 0, 0);
      acc1 = __builtin_amdgcn_mfma_f32_16x16x32_bf16(afr[ks], b1, acc1, 0, 0, 0);
    }
  }
  #pragma unroll
  for (int j = 0; j < 2; ++j) {
    f32x4 a = j ? acc1 : acc0;
    int px = (nt0 + j) * 16 + li;
    #pragma unroll
    for (int r = 0; r < 4; ++r) {
      int oc = mt * 16 + q * 4 + r;
      if (oc < 27)
        atomicAdd(&offm[((b * 27 + oc) * 64 + ho) * 64 + px], a[r]);
    }
  }
}

// ---------------- DCNv2 via MFMA, K-split 2, atomic accumulate ----------------
// grid 1024: block = (half, b, ho). M=128, N=64, K=576 per block (9 chunks of 64).
#define LW 72   // s_s row stride (shorts); 144 B = 16B-aligned

__global__ __launch_bounds__(256, 4)
void dcn_mfma_kernel(const float* __restrict__ x,
                     const unsigned short* __restrict__ wB,
                     const float* __restrict__ offm,
                     float* __restrict__ out) {
  __shared__ __align__(16) unsigned short s_s[64 * LW];  // 9216 B
  __shared__ __align__(16) uint2 s_idx[9 * 64];          // 4608 B (4 x u16 idx)
  __shared__ __align__(16) f32x4 s_wt[9 * 64];           // 9216 B
  const int t = threadIdx.x;
  const int bi = blockIdx.x & 511, half = blockIdx.x >> 9;
  const int b = bi >> 6, ho = bi & 63;
  const int lane = t & 63, wid = t >> 6;
  const int q = lane >> 4, li = lane & 15;
  const float* __restrict__ xb = x + (size_t)b * CI * 4096;
  const float* __restrict__ ob = offm + (size_t)b * 27 * 4096 + ho * 64;
  const int kbase = half * 576;

  // Per-(k,px) bilinear table (ci-invariant): packed corner idx + modulated weights
  for (int f = t; f < 576; f += 256) {
    int k = f >> 6, px = f & 63;
    int ky = k / 3, kx = k - ky * 3;
    float offy = ob[(2 * k    ) * 4096 + px];
    float offx = ob[(2 * k + 1) * 4096 + px];
    float m    = ob[(18 + k   ) * 4096 + px];
    float py  = offy + (float)(ho + ky - 1);
    float pxf = offx + (float)(px + kx - 1);
    float y0f = floorf(py), x0f = floorf(pxf);
    float wy = py - y0f, wx = pxf - x0f;
    int y0 = (int)y0f, x0 = (int)x0f;
    int y1 = y0 + 1, x1 = x0 + 1;
    bool y0v = (unsigned)y0 < 64u, y1v = (unsigned)y1 < 64u;
    bool x0v = (unsigned)x0 < 64u, x1v = (unsigned)x1 < 64u;
    int y0c = min(max(y0, 0), 63), y1c = min(max(y1, 0), 63);
    int x0c = min(max(x0, 0), 63), x1c = min(max(x1, 0), 63);
    unsigned i00 = (unsigned)(y0c * 64 + x0c), i01 = (unsigned)(y0c * 64 + x1c);
    unsigned i10 = (unsigned)(y1c * 64 + x0c), i11 = (unsigned)(y1c * 64 + x1c);
    uint2 ip; ip.x = i00 | (i01 << 16); ip.y = i10 | (i11 << 16);
    f32x4 wv;
    wv[0] = (y0v && x0v) ? (1.f - wy) * (1.f - wx) * m : 0.f;
    wv[1] = (y0v && x1v) ? (1.f - wy) * wx         * m : 0.f;
    wv[2] = (y1v && x0v) ? wy         * (1.f - wx) * m : 0.f;
    wv[3] = (y1v && x1v) ? wy         * wx         * m : 0.f;
    s_idx[f] = ip;
    s_wt[f]  = wv;
  }

  f32x4 acc[2][4];
  #pragma unroll
  for (int i = 0; i < 2; ++i)
    #pragma unroll
    for (int j = 0; j < 4; ++j) acc[i][j] = (f32x4){0.f, 0.f, 0.f, 0.f};

  for (int ch = 0; ch < 9; ++ch) {
    const int k0 = ch * 64;
    // prefetch A-fragments from L2-resident bf16 weights
    bf16x8 afr[2][2];
    #pragma unroll
    for (int ks = 0; ks < 2; ++ks)
      #pragma unroll
      for (int mt = 0; mt < 2; ++mt)
        afr[ks][mt] = *(const bf16x8*)&wB[(wid * 32 + mt * 16 + li) * KTOT +
                                          kbase + k0 + ks * 32 + q * 8];
    __syncthreads();  // table ready (first iter) / prev MFMA reads done
    // sampling: 8 k-groups x 64 px = 512 groups, 2 per thread, b128 stores
    #pragma unroll
    for (int g = 0; g < 2; ++g) {
      int f = t + g * 256;
      int px = f & 63, kg = f >> 6;    // kg 0..7
      int ki0 = kg * 8;
      bf16x8 vv;
      #pragma unroll
      for (int j = 0; j < 8; ++j) {
        int kk = kbase + k0 + ki0 + j;
        int cc = (int)((unsigned)kk / 9u);
        int k  = kk - cc * 9;
        uint2 ip = s_idx[k * 64 + px];
        f32x4 wv = s_wt[k * 64 + px];
        const float* __restrict__ xc = xb + cc * 4096;
        float v = wv[0] * xc[ip.x & 0xFFFF] + wv[1] * xc[ip.x >> 16] +
                  wv[2] * xc[ip.y & 0xFFFF] + wv[3] * xc[ip.y >> 16];
        vv[j] = (short)f2bf(v);
      }
      *(bf16x8*)&s_s[px * LW + ki0] = vv;
    }
    __syncthreads();
    #pragma unroll
    for (int ks = 0; ks < 2; ++ks) {
      const int kc = ks * 32 + q * 8;
      #pragma unroll
      for (int nt = 0; nt < 4; ++nt) {
        bf16x8 bb = *(const bf16x8*)&s_s[(nt * 16 + li) * LW + kc];
        acc[0][nt] = __builtin_amdgcn_mfma_f32_16x16x32_bf16(afr[ks][0], bb, acc[0][nt], 0, 0, 0);
        acc[1][nt] = __builtin_amdgcn_mfma_f32_16x16x32_bf16(afr[ks][1], bb, acc[1][nt], 0, 0, 0);
      }
    }
  }

  #pragma unroll
  for (int mt = 0; mt < 2; ++mt) {
    #pragma unroll
    for (int r = 0; r < 4; ++r) {
      int oc = wid * 32 + mt * 16 + q * 4 + r;
      float* orow = out + (((size_t)b * CO + oc) * 64 + ho) * 64;
      #pragma unroll
      for (int nt = 0; nt < 4; ++nt)
        atomicAdd(&orow[nt * 16 + li], acc[mt][nt][r]);
    }
  }
}

extern "C" void kernel_launch(void* const* d_in, const int* in_sizes, int n_in,
                              void* d_out, int out_size, void* d_ws, size_t ws_size,
                              hipStream_t stream) {
  const float* x     = (const float*)d_in[0];
  const float* w_off = (const float*)d_in[1];
  const float* b_off = (const float*)d_in[2];
  const float* w_def = (const float*)d_in[3];
  const float* b_def = (const float*)d_in[4];
  float* out = (float*)d_out;

  unsigned short* wsA = (unsigned short*)d_ws;
  unsigned short* wsB = wsA + NA_W;
  float* offm = (float*)((char*)d_ws + 2 * (NA_W + NB_W));

  const int prep_total = NA_W + NB_W + N_OFFM + N_OUT;   // 5263360
  prep_kernel<<<dim3(prep_total / 256), dim3(256), 0, stream>>>(
      w_off, w_def, b_def, wsA, wsB, offm, out);
  offset_conv_kernel<<<dim3(NB * 64 * 4), dim3(256), 0, stream>>>(x, wsA, offm);
  finalize_offm<<<dim3(N_OFFM / 256), dim3(256), 0, stream>>>(offm, b_off);
  dcn_mfma_kernel<<<dim3(NB * 64 * 2), dim3(256), 0, stream>>>(x, wsB, offm, out);
}

// Round 4
// 135.683 us; speedup vs baseline: 2.5503x; 2.5503x over previous
//
#include <hip/hip_runtime.h>
#include <math.h>

typedef _Float16 f16;
typedef __attribute__((ext_vector_type(2))) _Float16 f16x2;
typedef __attribute__((ext_vector_type(8))) _Float16 f16x8;
typedef __attribute__((ext_vector_type(4))) float f32x4;

#define NBATCH 8
#define WSA_ELE 36864      // 32*1152 (w_off padded to 32 rows, k-major, frag-swizzled)
#define WSB_ELE 147456     // 128*1152 (w_def, k-major, frag-swizzled)
// workspace byte offsets
#define OFF_WSB  73728
#define OFF_XT   368640
#define OFF_OFFM 8757248

__device__ __forceinline__ void gload_lds16(const f16* gsrc, f16* ldst) {
  // wave-uniform LDS base; HW adds lane*16
  __builtin_amdgcn_global_load_lds(
      (const __attribute__((address_space(1))) unsigned int*)gsrc,
      (__attribute__((address_space(3))) unsigned int*)ldst, 16, 0, 0);
}

// ---------------- prep: weights -> fp16, k-major, MFMA-fragment-swizzled ----------------
// swizzled element e = ((ch*NFRAG + mt)*64 + lane)*8 + j holds
// W[row = mt*16 + (lane&15)][kidx = ch*32 + (lane>>4)*8 + j], kidx = k*128 + cc.
__global__ __launch_bounds__(256) void prep_w_kernel(const float* __restrict__ w_off,
                                                     const float* __restrict__ w_def,
                                                     f16* __restrict__ wsA,
                                                     f16* __restrict__ wsB) {
  int i = blockIdx.x * 256 + threadIdx.x;
  if (i < WSA_ELE) {
    int j = i & 7, lane = (i >> 3) & 63, fm = i >> 9;
    int ch = fm >> 1, mt = fm & 1;
    int row = mt * 16 + (lane & 15);
    int kidx = ch * 32 + (lane >> 4) * 8 + j;
    int k = kidx >> 7, cc = kidx & 127;
    float v = (row < 27) ? w_off[row * 1152 + cc * 9 + k] : 0.0f;
    wsA[i] = (f16)v;
  } else {
    int e = i - WSA_ELE;
    int j = e & 7, lane = (e >> 3) & 63, fm = e >> 9;
    int ch = fm >> 3, mt = fm & 7;
    int row = mt * 16 + (lane & 15);
    int kidx = ch * 32 + (lane >> 4) * 8 + j;
    int k = kidx >> 7, cc = kidx & 127;
    wsB[e] = (f16)w_def[row * 1152 + cc * 9 + k];
  }
}

// ---------------- transpose: x NCHW fp32 -> x_t NHWC fp16 ----------------
__global__ __launch_bounds__(256) void transpose_kernel(const float* __restrict__ x,
                                                        f16* __restrict__ xt) {
  __shared__ f16 s_t[128 * 66];   // [c][p], pad 66 -> conflict-free
  const int t = threadIdx.x;
  const int b = blockIdx.x >> 6;
  const int pos0 = (blockIdx.x & 63) << 6;
  const float* xb = x + ((size_t)b << 19);
  for (int i = t; i < 8192; i += 256) {
    int c = i >> 6, p = i & 63;
    s_t[c * 66 + p] = (f16)xb[c * 4096 + pos0 + p];
  }
  __syncthreads();
  f16* xtb = xt + ((size_t)b << 19);
  for (int i = t; i < 4096; i += 256) {
    int p = i >> 6, c2 = (i & 63) * 2;
    unsigned v0 = *(const unsigned short*)&s_t[c2 * 66 + p];
    unsigned v1 = *(const unsigned short*)&s_t[(c2 + 1) * 66 + p];
    *(unsigned*)&xtb[(size_t)(pos0 + p) * 128 + c2] = v0 | (v1 << 16);
  }
}

// ---------------- offset conv: barrier-free im2col MFMA (M=32, k-major K) ----------------
__global__ __launch_bounds__(256) void offset_conv_kernel(const f16* __restrict__ xt,
                                                          const f16* __restrict__ wsA,
                                                          const float* __restrict__ b_off,
                                                          float* __restrict__ offm) {
  const int t = threadIdx.x;
  const int b = blockIdx.x >> 6, ho = blockIdx.x & 63;
  const int lane = t & 63, wid = t >> 6;
  const int q = lane >> 4, li = lane & 15;
  const int px = (wid << 4) + li;
  const char* xtb = (const char*)xt + ((size_t)b << 20);

  f32x4 acc0 = {0.f, 0.f, 0.f, 0.f}, acc1 = {0.f, 0.f, 0.f, 0.f};

  for (int k = 0; k < 9; ++k) {
    const int ky = k / 3, kx = k - ky * 3;
    const int y = ho + ky - 1;
    const int xx = px + kx - 1;
    const bool valid = ((unsigned)y < 64u) && ((unsigned)xx < 64u);
    const int pos = min(max(y, 0), 63) * 64 + min(max(xx, 0), 63);
    const int voff = pos * 256 + q * 16;   // bytes; +c4*64 as imm below
    #pragma unroll
    for (int c4 = 0; c4 < 4; ++c4) {
      union { uint4 u; f16x8 v; } bu;
      bu.u = *(const uint4*)(xtb + voff + c4 * 64);
      if (!valid) { bu.u.x = 0u; bu.u.y = 0u; bu.u.z = 0u; bu.u.w = 0u; }
      const int ch = k * 4 + c4;
      f16x8 a0 = *(const f16x8*)&wsA[(ch * 2    ) * 512 + lane * 8];
      f16x8 a1 = *(const f16x8*)&wsA[(ch * 2 + 1) * 512 + lane * 8];
      acc0 = __builtin_amdgcn_mfma_f32_16x16x32_f16(a0, bu.v, acc0, 0, 0, 0);
      acc1 = __builtin_amdgcn_mfma_f32_16x16x32_f16(a1, bu.v, acc1, 0, 0, 0);
    }
  }

  float* om = offm + (size_t)b * 27 * 4096 + ho * 64 + px;
  #pragma unroll
  for (int mt = 0; mt < 2; ++mt) {
    f32x4 a = mt ? acc1 : acc0;
    #pragma unroll
    for (int r = 0; r < 4; ++r) {
      int oc = mt * 16 + q * 4 + r;
      if (oc < 27) {
        float v = a[r] + b_off[oc];
        if (oc >= 18) v = 1.0f / (1.0f + __expf(-v));
        om[oc * 4096] = v;
      }
    }
  }
}

// ---------------- DCNv2: reg-sampled B (packed fp16 bilinear) + LDS-dbuf A ----------------
__global__ __launch_bounds__(256) void dcn_kernel(const f16* __restrict__ xt,
                                                  const f16* __restrict__ wsB,
                                                  const float* __restrict__ offm,
                                                  const float* __restrict__ b_def,
                                                  float* __restrict__ out) {
  __shared__ uint4  s_ofs[576];                 // 9216 B: per-(k,px) corner byte-offsets
  __shared__ float4 s_wt[576];                  // 9216 B: per-(k,px) modulated weights
  __shared__ __align__(16) f16 s_a[2][4096];    // 2 x 8 KB A double-buffer
  const int t = threadIdx.x;
  const int b = blockIdx.x >> 6, ho = blockIdx.x & 63;
  const int lane = t & 63, wid = t >> 6;
  const int q = lane >> 4, li = lane & 15;
  const int px0 = wid << 4;
  const char* xtb = (const char*)xt + ((size_t)b << 20);

  // stage chunk 0 A early (latency hidden under table build)
  {
    const int seg = wid * 2;
    gload_lds16(wsB + seg * 512 + lane * 8,       &s_a[0][seg * 512]);
    gload_lds16(wsB + (seg + 1) * 512 + lane * 8, &s_a[0][(seg + 1) * 512]);
  }

  // bilinear table: ci-invariant corner offsets + mask-premultiplied weights
  const float* ob = offm + (size_t)b * 27 * 4096 + ho * 64;
  for (int f = t; f < 576; f += 256) {
    int k = f >> 6, p = f & 63;
    int ky = k / 3, kx = k - ky * 3;
    float oy = ob[(2 * k    ) * 4096 + p];
    float ox = ob[(2 * k + 1) * 4096 + p];
    float m  = ob[(18 + k   ) * 4096 + p];
    float py  = oy + (float)(ho + ky - 1);
    float pxf = ox + (float)(p + kx - 1);
    float y0f = floorf(py), x0f = floorf(pxf);
    float wy = py - y0f, wx = pxf - x0f;
    int y0 = (int)y0f, x0 = (int)x0f;
    int y1 = y0 + 1, x1 = x0 + 1;
    bool y0v = (unsigned)y0 < 64u, y1v = (unsigned)y1 < 64u;
    bool x0v = (unsigned)x0 < 64u, x1v = (unsigned)x1 < 64u;
    int y0c = min(max(y0, 0), 63), y1c = min(max(y1, 0), 63);
    int x0c = min(max(x0, 0), 63), x1c = min(max(x1, 0), 63);
    uint4 o4;
    o4.x = (unsigned)((y0c * 64 + x0c) * 256);
    o4.y = (unsigned)((y0c * 64 + x1c) * 256);
    o4.z = (unsigned)((y1c * 64 + x0c) * 256);
    o4.w = (unsigned)((y1c * 64 + x1c) * 256);
    float4 w4;
    w4.x = (y0v && x0v) ? (1.f - wy) * (1.f - wx) * m : 0.f;
    w4.y = (y0v && x1v) ? (1.f - wy) * wx         * m : 0.f;
    w4.z = (y1v && x0v) ? wy         * (1.f - wx) * m : 0.f;
    w4.w = (y1v && x1v) ? wy         * wx         * m : 0.f;
    s_ofs[f] = o4;
    s_wt[f]  = w4;
  }
  __syncthreads();   // table ready + chunk-0 staging drained (vmcnt before barrier)

  f32x4 acc[8];
  #pragma unroll
  for (int mt = 0; mt < 8; ++mt) acc[mt] = (f32x4){0.f, 0.f, 0.f, 0.f};

  for (int k = 0; k < 9; ++k) {
    const int e = k * 64 + px0 + li;
    const uint4  o4 = s_ofs[e];
    const float4 w4 = s_wt[e];
    const unsigned voff0 = o4.x + q * 16, voff1 = o4.y + q * 16;
    const unsigned voff2 = o4.z + q * 16, voff3 = o4.w + q * 16;
    const f16 h0 = (f16)w4.x, h1 = (f16)w4.y, h2 = (f16)w4.z, h3 = (f16)w4.w;
    const f16x2 wp0 = {h0, h0}, wp1 = {h1, h1}, wp2 = {h2, h2}, wp3 = {h3, h3};
    #pragma unroll
    for (int c4 = 0; c4 < 4; ++c4) {
      const int ch = k * 4 + c4;
      if (ch < 35) {   // stage next chunk into the other buffer
        const int nb = (ch + 1) & 1;
        const int seg = wid * 2;
        const f16* src = wsB + (ch + 1) * 4096;
        gload_lds16(src + seg * 512 + lane * 8,       &s_a[nb][seg * 512]);
        gload_lds16(src + (seg + 1) * 512 + lane * 8, &s_a[nb][(seg + 1) * 512]);
      }
      union { uint4 u; f16x2 h[4]; } d0, d1, d2, d3;
      d0.u = *(const uint4*)(xtb + voff0 + c4 * 64);
      d1.u = *(const uint4*)(xtb + voff1 + c4 * 64);
      d2.u = *(const uint4*)(xtb + voff2 + c4 * 64);
      d3.u = *(const uint4*)(xtb + voff3 + c4 * 64);
      union { f16x2 h[4]; f16x8 v; } bf;
      #pragma unroll
      for (int i = 0; i < 4; ++i) {
        f16x2 s = d0.h[i] * wp0;
        s = s + d1.h[i] * wp1;
        s = s + d2.h[i] * wp2;
        s = s + d3.h[i] * wp3;
        bf.h[i] = s;
      }
      const f16* ab = &s_a[ch & 1][0];
      #pragma unroll
      for (int mt = 0; mt < 8; ++mt) {
        f16x8 a = *(const f16x8*)&ab[(mt * 64 + lane) * 8];
        acc[mt] = __builtin_amdgcn_mfma_f32_16x16x32_f16(a, bf.v, acc[mt], 0, 0, 0);
      }
      __syncthreads();   // drain staging + protect buffer swap
    }
  }

  float* o = out + (size_t)b * 128 * 4096 + ho * 64 + px0 + li;
  #pragma unroll
  for (int mt = 0; mt < 8; ++mt) {
    #pragma unroll
    for (int r = 0; r < 4; ++r) {
      int oc = mt * 16 + q * 4 + r;
      o[oc * 4096] = acc[mt][r] + b_def[oc];
    }
  }
}

extern "C" void kernel_launch(void* const* d_in, const int* in_sizes, int n_in,
                              void* d_out, int out_size, void* d_ws, size_t ws_size,
                              hipStream_t stream) {
  const float* x     = (const float*)d_in[0];
  const float* w_off = (const float*)d_in[1];
  const float* b_off = (const float*)d_in[2];
  const float* w_def = (const float*)d_in[3];
  const float* b_def = (const float*)d_in[4];
  float* out = (float*)d_out;

  f16*   wsA  = (f16*)d_ws;
  f16*   wsB  = (f16*)((char*)d_ws + OFF_WSB);
  f16*   xt   = (f16*)((char*)d_ws + OFF_XT);
  float* offm = (float*)((char*)d_ws + OFF_OFFM);

  prep_w_kernel<<<dim3((WSA_ELE + WSB_ELE) / 256), dim3(256), 0, stream>>>(w_off, w_def, wsA, wsB);
  transpose_kernel<<<dim3(NBATCH * 64), dim3(256), 0, stream>>>(x, xt);
  offset_conv_kernel<<<dim3(NBATCH * 64), dim3(256), 0, stream>>>(xt, wsA, b_off, offm);
  dcn_kernel<<<dim3(NBATCH * 64), dim3(256), 0, stream>>>(xt, wsB, offm, b_def, out);
}